// Round 4
// baseline (303.801 us; speedup 1.0000x reference)
//
#include <hip/hip_runtime.h>
#include <hip/hip_bf16.h>
#include <math.h>

// Problem constants: x[B=16][T=4096][D=512], W[512][512], v[512]
#define BB 16
#define TT 4096
#define DD 512
#define MM (BB*TT)   // 65536 rows

typedef __bf16 bf16x8 __attribute__((ext_vector_type(8)));
typedef float  f32x4  __attribute__((ext_vector_type(4)));

__device__ inline unsigned short f2bf(float f) {
    unsigned u = __builtin_bit_cast(unsigned, f) + 0x8000u;  // round-half-away
    return (unsigned short)(u >> 16);
}

// pack two fp32 -> two bf16 in one u32 (2 v_add + 1 v_perm)
__device__ inline unsigned pack_bf16x2(float lo, float hi) {
    unsigned u0 = __builtin_bit_cast(unsigned, lo) + 0x8000u;
    unsigned u1 = __builtin_bit_cast(unsigned, hi) + 0x8000u;
    return __builtin_amdgcn_perm(u1, u0, 0x07060302);  // [u1.hi16, u0.hi16]
}

// fast tanh: 1 - 2/(e^{2y}+1).  |y| <~ 1.5 here, no overflow concerns.
__device__ inline float tanh_fast(float y) {
    float e = __expf(2.0f * y);
    return 1.0f - 2.0f * __builtin_amdgcn_rcpf(e + 1.0f);
}

// ---------------- Kernel: W[k][n] fp32 -> Wt[n][k] bf16 ----------------
__global__ void wt_kernel(const float* __restrict__ W, unsigned short* __restrict__ Wt) {
    int idx = blockIdx.x * 256 + threadIdx.x;   // coalesced writes
    int n = idx >> 9;
    int k = idx & 511;
    Wt[idx] = f2bf(W[k * DD + n]);              // strided reads absorbed by L2 (W = 1 MB)
}

// ---------------- Fused GEMM + tanh + v-dot -> final scores ----------------
// Block = 64 rows x full N=512 x full K=512.  4 waves; wave w owns cols [w*128, +128)
// as 2 passes of a 64x64 accumulator (4x4 16x16x32 MFMA tiles, full-K accumulation).
// A-strip (64x512 bf16 = 64 KB) staged once into LDS (fp32->bf16, XOR chunk swizzle,
// conflict-free ds_read_b128).  B (Wt, L2-resident) read global->VGPR through a
// 4-deep ring (3-step lookahead ~ L2 latency).  ZERO barriers in the K-loop.
// Staging loop unroll capped at 4: full unroll put 32 dwordx4 loads in flight
// (128 VGPRs) -> spills (R3: WRITE_SIZE 37 MB of scratch).
__global__ __launch_bounds__(256, 2) void scores_kernel(
        const float* __restrict__ x, const unsigned short* __restrict__ Wt,
        const float* __restrict__ v, float* __restrict__ scores) {
    __shared__ unsigned short As[64 * DD];   // 64 KB
    __shared__ float sbuf[4][64];

    const int tid  = threadIdx.x;
    const int m0   = blockIdx.x * 64;
    const int wid  = tid >> 6;
    const int lane = tid & 63;
    const int l15  = lane & 15;
    const int q    = lane >> 4;
    const int r3   = l15 & 7;

    // B fragment loader: row n = base+ni*16+l15, k = s*32 + q*8 (16 B)
    const unsigned short* bbase = Wt + (size_t)(wid * 128 + l15) * DD + q * 8;
#define LOAD_B(p, ni, s) (*(const bf16x8*)(bbase + (size_t)((p) * 64 + (ni) * 16) * DD + (s) * 32))

    // Prime p=0's B ring BEFORE staging/barrier: latency hides under the A stage.
    bf16x8 b[4][4];
    #pragma unroll
    for (int s = 0; s < 3; s++)
        #pragma unroll
        for (int ni = 0; ni < 4; ni++)
            b[s][ni] = LOAD_B(0, ni, s);

    // ---- Stage A: 64 rows x 512 cols fp32 -> bf16, swizzled.
    // Wave-iter = one full row (64 lanes x 32 B = 2 KB contiguous global read).
    #pragma unroll 4
    for (int i = 0; i < 16; i++) {
        int u = i * 256 + tid;           // 0..4095 (16-B output chunk id)
        int r = u >> 6;                  // 64 chunks per row
        int c = u & 63;
        const float* gp = x + (size_t)(m0 + r) * DD + c * 8;
        float4 f0 = *(const float4*)(gp);
        float4 f1 = *(const float4*)(gp + 4);
        uint4 o;
        o.x = pack_bf16x2(f0.x, f0.y);
        o.y = pack_bf16x2(f0.z, f0.w);
        o.z = pack_bf16x2(f1.x, f1.y);
        o.w = pack_bf16x2(f1.z, f1.w);
        *(uint4*)(&As[r * DD + (c ^ (r & 7)) * 8]) = o;
    }
    __syncthreads();   // the only barrier before the epilogue

    float vpart[4][4];
    #pragma unroll
    for (int mi = 0; mi < 4; mi++)
        #pragma unroll
        for (int rr = 0; rr < 4; rr++)
            vpart[mi][rr] = 0.f;

    // A-frag LDS address (ushort units): row R = mi*16+l15, k-step s, quarter q
    //   chunk = (s*4+q) ^ r3  (XOR swizzle); addr = R*512 + chunk*8
#define A_FRAG(mi, s) (*(const bf16x8*)(&As[((mi)*16 + l15) * DD + ((((s)*4 + q) ^ r3) * 8)]))

    #pragma unroll
    for (int p = 0; p < 2; p++) {
        if (p == 1) {   // re-prime ring for second 64-col pass
            #pragma unroll
            for (int s = 0; s < 3; s++)
                #pragma unroll
                for (int ni = 0; ni < 4; ni++)
                    b[s][ni] = LOAD_B(1, ni, s);
        }

        f32x4 acc[4][4];
        #pragma unroll
        for (int mi = 0; mi < 4; mi++)
            #pragma unroll
            for (int ni = 0; ni < 4; ni++)
                acc[mi][ni] = (f32x4){0.f, 0.f, 0.f, 0.f};

        bf16x8 a[2][4];
        #pragma unroll
        for (int mi = 0; mi < 4; mi++) a[0][mi] = A_FRAG(mi, 0);

        #pragma unroll
        for (int s = 0; s < 16; s++) {
            const int cur = s & 1;
            if (s < 15) {
                #pragma unroll
                for (int mi = 0; mi < 4; mi++) a[cur ^ 1][mi] = A_FRAG(mi, s + 1);
            }
            if (s < 13) {
                #pragma unroll
                for (int ni = 0; ni < 4; ni++)
                    b[(s + 3) & 3][ni] = LOAD_B(p, ni, s + 3);
            }
            #pragma unroll
            for (int mi = 0; mi < 4; mi++)
                #pragma unroll
                for (int ni = 0; ni < 4; ni++)
                    acc[mi][ni] = __builtin_amdgcn_mfma_f32_16x16x32_bf16(
                        a[cur][mi], b[s & 3][ni], acc[mi][ni], 0, 0, 0);
        }

        // epilogue: tanh + v-dot into per-row partials
        // C/D layout (16x16): col = lane&15, row = q*4 + rr  [m89/m91 verified]
        float vv[4];
        #pragma unroll
        for (int ni = 0; ni < 4; ni++)
            vv[ni] = v[wid * 128 + p * 64 + ni * 16 + l15];
        #pragma unroll
        for (int mi = 0; mi < 4; mi++)
            #pragma unroll
            for (int ni = 0; ni < 4; ni++)
                #pragma unroll
                for (int rr = 0; rr < 4; rr++)
                    vpart[mi][rr] += tanh_fast(acc[mi][ni][rr]) * vv[ni];
    }
#undef A_FRAG
#undef LOAD_B

    // cross-lane reduce over the 16 col-lanes, then cross-wave via LDS
    #pragma unroll
    for (int mi = 0; mi < 4; mi++)
        #pragma unroll
        for (int rr = 0; rr < 4; rr++) {
            float sum = vpart[mi][rr];
            sum += __shfl_xor(sum, 1);
            sum += __shfl_xor(sum, 2);
            sum += __shfl_xor(sum, 4);
            sum += __shfl_xor(sum, 8);
            if (l15 == 0)
                sbuf[wid][mi * 16 + q * 4 + rr] = sum;
        }
    __syncthreads();
    if (tid < 64)
        scores[m0 + tid] = sbuf[0][tid] + sbuf[1][tid] + sbuf[2][tid] + sbuf[3][tid];
}

// ---------------- Softmax over T per batch ----------------
__global__ void softmax_kernel(const float* __restrict__ scores, float* __restrict__ weights) {
    const int b = blockIdx.x;
    const int tid = threadIdx.x;     // 256 threads, 16 elems each
    __shared__ float wred[4];

    float s[16];
    float mx = -1e30f;
    #pragma unroll
    for (int i = 0; i < 16; i++) {
        float sv = scores[b * TT + i * 256 + tid];
        s[i] = sv;
        mx = fmaxf(mx, sv);
    }
    #pragma unroll
    for (int off = 32; off; off >>= 1) mx = fmaxf(mx, __shfl_xor(mx, off));
    if ((tid & 63) == 0) wred[tid >> 6] = mx;
    __syncthreads();
    mx = fmaxf(fmaxf(wred[0], wred[1]), fmaxf(wred[2], wred[3]));
    __syncthreads();

    float sum = 0.f;
    #pragma unroll
    for (int i = 0; i < 16; i++) { s[i] = __expf(s[i] - mx); sum += s[i]; }
    #pragma unroll
    for (int off = 32; off; off >>= 1) sum += __shfl_xor(sum, off);
    if ((tid & 63) == 0) wred[tid >> 6] = sum;
    __syncthreads();
    sum = wred[0] + wred[1] + wred[2] + wred[3];

    const float inv = 1.0f / sum;
    #pragma unroll
    for (int i = 0; i < 16; i++)
        weights[b * TT + i * 256 + tid] = s[i] * inv;
}

// ---------------- Pooling: out[b,d] = sum_t w[b,t] * x[b,t,d] ----------------
// 256 blocks x 256 thr; thread = (ts = tid>>7, dq = tid&127); float4 (16 B/lane),
// unroll 8 -> ~32 float4 in flight per wave-group; HBM-ceiling target.
#define PTCH 256
__global__ void pool_kernel(const float* __restrict__ x, const float* __restrict__ weights,
                            float* __restrict__ out) {
    __shared__ float wsm[PTCH];
    const int b   = blockIdx.y;
    const int t0  = blockIdx.x * PTCH;
    const int tid = threadIdx.x;
    wsm[tid] = weights[b * TT + t0 + tid];
    __syncthreads();

    const int dq = tid & 127;    // float4 column
    const int ts = tid >> 7;     // t parity
    f32x4 acc = (f32x4){0.f, 0.f, 0.f, 0.f};
    const float* xp = x + ((size_t)b * TT + t0) * DD + dq * 4;
    #pragma unroll 8
    for (int t = ts; t < PTCH; t += 2) {
        f32x4 xv = *(const f32x4*)(xp + (size_t)t * DD);
        float w = wsm[t];
        acc += w * xv;
    }
    float* op = out + b * DD + dq * 4;
    atomicAdd(op + 0, acc[0]);
    atomicAdd(op + 1, acc[1]);
    atomicAdd(op + 2, acc[2]);
    atomicAdd(op + 3, acc[3]);
}

extern "C" void kernel_launch(void* const* d_in, const int* in_sizes, int n_in,
                              void* d_out, int out_size, void* d_ws, size_t ws_size,
                              hipStream_t stream) {
    (void)in_sizes; (void)n_in; (void)out_size; (void)ws_size;
    const float* x = (const float*)d_in[0];
    const float* W = (const float*)d_in[1];
    const float* v = (const float*)d_in[2];
    float* out = (float*)d_out;

    // ws layout: Wt bf16 (512 KB) | scores fp32 (256 KB) | weights fp32 (256 KB)
    unsigned short* Wt = (unsigned short*)d_ws;
    float* scores      = (float*)((char*)d_ws + 512 * 1024);
    float* weights     = (float*)((char*)d_ws + 512 * 1024 + 256 * 1024);

    hipMemsetAsync(d_out, 0, BB * DD * sizeof(float), stream);

    wt_kernel<<<DD * DD / 256, 256, 0, stream>>>(W, Wt);

    scores_kernel<<<MM / 64, 256, 0, stream>>>(x, Wt, v, scores);

    softmax_kernel<<<BB, 256, 0, stream>>>(scores, weights);

    pool_kernel<<<dim3(TT / PTCH, BB), 256, 0, stream>>>(x, weights, out);
}

// Round 5
// 289.732 us; speedup vs baseline: 1.0486x; 1.0486x over previous
//
#include <hip/hip_runtime.h>
#include <hip/hip_bf16.h>
#include <math.h>

// Problem constants: x[B=16][T=4096][D=512], W[512][512], v[512]
#define BB 16
#define TT 4096
#define DD 512
#define MM (BB*TT)   // 65536 rows

typedef __bf16 bf16x8 __attribute__((ext_vector_type(8)));
typedef float  f32x4  __attribute__((ext_vector_type(4)));

__device__ inline unsigned short f2bf(float f) {
    unsigned u = __builtin_bit_cast(unsigned, f) + 0x8000u;  // round-half-away
    return (unsigned short)(u >> 16);
}

// pack two fp32 -> two bf16 in one u32 (2 v_add + 1 v_perm)
__device__ inline unsigned pack_bf16x2(float lo, float hi) {
    unsigned u0 = __builtin_bit_cast(unsigned, lo) + 0x8000u;
    unsigned u1 = __builtin_bit_cast(unsigned, hi) + 0x8000u;
    return __builtin_amdgcn_perm(u1, u0, 0x07060302);  // [u1.hi16, u0.hi16]
}

// fast tanh: 1 - 2/(e^{2y}+1).  |y| <~ 1.5 here, no overflow concerns.
__device__ inline float tanh_fast(float y) {
    float e = __expf(2.0f * y);
    return 1.0f - 2.0f * __builtin_amdgcn_rcpf(e + 1.0f);
}

// ---------------- W[k][n] fp32 -> Wb bf16 in MFMA-fragment order ----------------
// Fragment (nf, s) = 64 lanes x 16 B contiguous (1 KB): lane holds
// B[k = s*32 + (lane>>4)*8 + j][n = nf*16 + (lane&15)], j=0..7.
// K-loop B loads become perfectly coalesced 1 KB wave reads.
__global__ void wb_kernel(const float* __restrict__ W, unsigned short* __restrict__ Wb) {
    int u = blockIdx.x * 256 + threadIdx.x;   // 0..32767 (frag-lane id)
    int lane = u & 63;
    int s  = (u >> 6) & 15;
    int nf = u >> 10;                         // 0..31
    int n  = nf * 16 + (lane & 15);
    int k0 = s * 32 + (lane >> 4) * 8;
    unsigned short o[8];
    #pragma unroll
    for (int j = 0; j < 8; j++) o[j] = f2bf(W[(size_t)(k0 + j) * DD + n]);
    *(uint4*)(Wb + (size_t)u * 8) = *(uint4*)o;   // coalesced 16 B store
}

// ---------------- Fused GEMM + tanh + v-dot -> final scores ----------------
// Block = 64 rows x full N=512 x full K=512.  4 waves; per pass p (4 passes) wave w
// owns cols [(p*4+w)*32, +32) as a 4x2 frag tile (16x16x32 MFMA, full-K accumulate).
// A-strip (64x512 bf16 = 64 KB) staged ONCE into LDS (fp32->bf16, XOR chunk swizzle,
// conflict-free ds_read_b128).  B read from fragment-ordered Wb (L2-resident) via a
// 4-deep ring, coalesced 1 KB wave loads.  ZERO barriers in the K-loop.
// Register budget (R3/R4 lesson): acc 32 + B-ring 32 + A-dbuf 32 + vpart 16 ~= 110
// arch regs -> no spill at the 128-arch split.
__global__ __launch_bounds__(256, 2) void scores_kernel(
        const float* __restrict__ x, const unsigned short* __restrict__ Wb,
        const float* __restrict__ v, float* __restrict__ scores) {
    __shared__ unsigned short As[64 * DD];   // 64 KB
    __shared__ float sbuf[4][64];

    const int tid  = threadIdx.x;
    const int m0   = blockIdx.x * 64;
    const int wid  = tid >> 6;
    const int lane = tid & 63;
    const int l15  = lane & 15;
    const int q    = lane >> 4;
    const int r3   = l15 & 7;

    const unsigned short* bw = Wb + (size_t)lane * 8;
    // frag (nf = (p*4+wid)*2+ni, s) at elem offset (nf*16+s)*512 + lane*8
#define BFRAG(p, ni, s) (*(const bf16x8*)(bw + ((size_t)((((p)*4 + wid)*2 + (ni))*16 + (s)) * 512)))
    // A-frag: row R = mi*16+l15, logical chunk c = s*4+q, stored at c^(R&7)
#define A_FRAG(mi, s) (*(const bf16x8*)(&As[((mi)*16 + l15) * DD + ((((s)*4 + q) ^ r3) * 8)]))

    // Prime p=0's B ring BEFORE staging: L2 latency hides under the A stage.
    bf16x8 b[4][2];
    #pragma unroll
    for (int s = 0; s < 3; s++) {
        b[s][0] = BFRAG(0, 0, s);
        b[s][1] = BFRAG(0, 1, s);
    }

    // ---- Stage A: 64 rows x 512 cols fp32 -> bf16, swizzled.
    // Wave-iter = one full row (64 lanes x 32 B = 2 KB contiguous global read).
    #pragma unroll 4
    for (int i = 0; i < 16; i++) {
        int u = i * 256 + tid;           // 0..4095 (16-B output chunk id)
        int r = u >> 6;                  // 64 chunks per row
        int c = u & 63;
        const float* gp = x + (size_t)(m0 + r) * DD + c * 8;
        float4 f0 = *(const float4*)(gp);
        float4 f1 = *(const float4*)(gp + 4);
        uint4 o;
        o.x = pack_bf16x2(f0.x, f0.y);
        o.y = pack_bf16x2(f0.z, f0.w);
        o.z = pack_bf16x2(f1.x, f1.y);
        o.w = pack_bf16x2(f1.z, f1.w);
        *(uint4*)(&As[r * DD + (c ^ (r & 7)) * 8]) = o;
    }
    __syncthreads();   // the only barrier before the epilogue

    float vpart[4][4];
    #pragma unroll
    for (int mi = 0; mi < 4; mi++)
        #pragma unroll
        for (int rr = 0; rr < 4; rr++)
            vpart[mi][rr] = 0.f;

    #pragma unroll
    for (int p = 0; p < 4; p++) {
        if (p > 0) {   // re-prime ring for this pass's cols
            #pragma unroll
            for (int s = 0; s < 3; s++) {
                b[s][0] = BFRAG(p, 0, s);
                b[s][1] = BFRAG(p, 1, s);
            }
        }

        f32x4 acc[4][2];
        #pragma unroll
        for (int mi = 0; mi < 4; mi++)
            #pragma unroll
            for (int ni = 0; ni < 2; ni++)
                acc[mi][ni] = (f32x4){0.f, 0.f, 0.f, 0.f};

        bf16x8 a[2][4];
        #pragma unroll
        for (int mi = 0; mi < 4; mi++) a[0][mi] = A_FRAG(mi, 0);

        #pragma unroll
        for (int s = 0; s < 16; s++) {
            const int cur = s & 1;
            if (s < 15) {
                #pragma unroll
                for (int mi = 0; mi < 4; mi++) a[cur ^ 1][mi] = A_FRAG(mi, s + 1);
            }
            if (s < 13) {
                b[(s + 3) & 3][0] = BFRAG(p, 0, s + 3);
                b[(s + 3) & 3][1] = BFRAG(p, 1, s + 3);
            }
            #pragma unroll
            for (int mi = 0; mi < 4; mi++)
                #pragma unroll
                for (int ni = 0; ni < 2; ni++)
                    acc[mi][ni] = __builtin_amdgcn_mfma_f32_16x16x32_bf16(
                        a[cur][mi], b[s & 3][ni], acc[mi][ni], 0, 0, 0);
        }

        // epilogue: tanh + v-dot into per-row partials
        // C/D layout (16x16): col = lane&15, row = q*4 + rr  [m89/m91 verified]
        float vv[2];
        vv[0] = v[(p * 4 + wid) * 32 + l15];
        vv[1] = v[(p * 4 + wid) * 32 + 16 + l15];
        #pragma unroll
        for (int mi = 0; mi < 4; mi++)
            #pragma unroll
            for (int ni = 0; ni < 2; ni++)
                #pragma unroll
                for (int rr = 0; rr < 4; rr++)
                    vpart[mi][rr] += tanh_fast(acc[mi][ni][rr]) * vv[ni];
    }
#undef A_FRAG
#undef BFRAG

    // cross-lane reduce over the 16 col-lanes, then cross-wave via LDS
    #pragma unroll
    for (int mi = 0; mi < 4; mi++)
        #pragma unroll
        for (int rr = 0; rr < 4; rr++) {
            float sum = vpart[mi][rr];
            sum += __shfl_xor(sum, 1);
            sum += __shfl_xor(sum, 2);
            sum += __shfl_xor(sum, 4);
            sum += __shfl_xor(sum, 8);
            if (l15 == 0)
                sbuf[wid][mi * 16 + q * 4 + rr] = sum;
        }
    __syncthreads();
    if (tid < 64)
        scores[m0 + tid] = sbuf[0][tid] + sbuf[1][tid] + sbuf[2][tid] + sbuf[3][tid];
}

// ---------------- Softmax over T per batch ----------------
__global__ void softmax_kernel(const float* __restrict__ scores, float* __restrict__ weights) {
    const int b = blockIdx.x;
    const int tid = threadIdx.x;     // 256 threads, 16 elems each
    __shared__ float wred[4];

    float s[16];
    float mx = -1e30f;
    #pragma unroll
    for (int i = 0; i < 16; i++) {
        float sv = scores[b * TT + i * 256 + tid];
        s[i] = sv;
        mx = fmaxf(mx, sv);
    }
    #pragma unroll
    for (int off = 32; off; off >>= 1) mx = fmaxf(mx, __shfl_xor(mx, off));
    if ((tid & 63) == 0) wred[tid >> 6] = mx;
    __syncthreads();
    mx = fmaxf(fmaxf(wred[0], wred[1]), fmaxf(wred[2], wred[3]));
    __syncthreads();

    float sum = 0.f;
    #pragma unroll
    for (int i = 0; i < 16; i++) { s[i] = __expf(s[i] - mx); sum += s[i]; }
    #pragma unroll
    for (int off = 32; off; off >>= 1) sum += __shfl_xor(sum, off);
    if ((tid & 63) == 0) wred[tid >> 6] = sum;
    __syncthreads();
    sum = wred[0] + wred[1] + wred[2] + wred[3];

    const float inv = 1.0f / sum;
    #pragma unroll
    for (int i = 0; i < 16; i++)
        weights[b * TT + i * 256 + tid] = s[i] * inv;
}

// ---------------- Pooling: out[b,d] = sum_t w[b,t] * x[b,t,d] ----------------
// 1024 blocks (4/CU) x 256 thr; lane = float4 column, two t-phases combined in LDS
// before 4 atomics/thread (atomic count same as R1's proven version).
#define PTCH 64
__global__ __launch_bounds__(256) void pool_kernel(
        const float* __restrict__ x, const float* __restrict__ weights,
        float* __restrict__ out) {
    __shared__ float wsm[PTCH];
    __shared__ f32x4 psum[128];
    const int b   = blockIdx.y;
    const int t0  = blockIdx.x * PTCH;
    const int tid = threadIdx.x;
    if (tid < PTCH) wsm[tid] = weights[b * TT + t0 + tid];
    __syncthreads();

    const int dq = tid & 127;    // float4 column 0..127
    const int ts = tid >> 7;     // t parity
    f32x4 acc = (f32x4){0.f, 0.f, 0.f, 0.f};
    const float* xp = x + ((size_t)b * TT + t0 + ts) * DD + dq * 4;
    #pragma unroll 8
    for (int t = ts; t < PTCH; t += 2) {
        f32x4 xv = *(const f32x4*)xp;
        acc += wsm[t] * xv;
        xp += 2 * DD;
    }
    if (ts == 1) psum[dq] = acc;
    __syncthreads();
    if (ts == 0) {
        acc += psum[dq];
        float* op = out + b * DD + dq * 4;
        atomicAdd(op + 0, acc[0]);
        atomicAdd(op + 1, acc[1]);
        atomicAdd(op + 2, acc[2]);
        atomicAdd(op + 3, acc[3]);
    }
}

extern "C" void kernel_launch(void* const* d_in, const int* in_sizes, int n_in,
                              void* d_out, int out_size, void* d_ws, size_t ws_size,
                              hipStream_t stream) {
    (void)in_sizes; (void)n_in; (void)out_size; (void)ws_size;
    const float* x = (const float*)d_in[0];
    const float* W = (const float*)d_in[1];
    const float* v = (const float*)d_in[2];
    float* out = (float*)d_out;

    // ws layout: Wb bf16 frag-order (512 KB) | scores fp32 (256 KB) | weights fp32 (256 KB)
    unsigned short* Wb = (unsigned short*)d_ws;
    float* scores      = (float*)((char*)d_ws + 512 * 1024);
    float* weights     = (float*)((char*)d_ws + 512 * 1024 + 256 * 1024);

    hipMemsetAsync(d_out, 0, BB * DD * sizeof(float), stream);

    wb_kernel<<<128, 256, 0, stream>>>(W, Wb);

    scores_kernel<<<MM / 64, 256, 0, stream>>>(x, Wb, v, scores);

    softmax_kernel<<<BB, 256, 0, stream>>>(scores, weights);

    pool_kernel<<<dim3(TT / PTCH, BB), 256, 0, stream>>>(x, weights, out);
}